// Round 21
// baseline (55993.890 us; speedup 1.0000x reference)
//
#include <hip/hip_runtime.h>
#include <stdint.h>

#define T_STEPS 25
#define BATCH   1024
#define IN_F    784
#define HID     4096
#define OUTF    10
// Eigen SINGLE-THREADED gebp blocking (verified bit-exact R11-R20):
// max_kc=288 evened -> kc(784)=264 (264+264+256), kc(4096)=280 (14x280+176).
#define KC_L0   264
#define KC_L1   280
#define KCHUNK  128

typedef float v2f __attribute__((ext_vector_type(2)));

// ---------------- Threefry-2x32, key = (0, 42), 20 rounds ----------------
__device__ __forceinline__ uint32_t rotl32(uint32_t x, int d) {
    return (x << d) | (x >> (32 - d));
}

__device__ __forceinline__ void threefry2x32_42(uint32_t x0, uint32_t x1,
                                                uint32_t& r0, uint32_t& r1) {
    const uint32_t k0 = 0u, k1 = 42u;
    const uint32_t k2 = k0 ^ k1 ^ 0x1BD11BDAu;
    x0 += k0; x1 += k1;
#define TF_ROUND(r) { x0 += x1; x1 = rotl32(x1, r); x1 ^= x0; }
    TF_ROUND(13) TF_ROUND(15) TF_ROUND(26) TF_ROUND(6)
    x0 += k1; x1 += k2 + 1u;
    TF_ROUND(17) TF_ROUND(29) TF_ROUND(16) TF_ROUND(24)
    x0 += k2; x1 += k0 + 2u;
    TF_ROUND(13) TF_ROUND(15) TF_ROUND(26) TF_ROUND(6)
    x0 += k0; x1 += k1 + 3u;
    TF_ROUND(17) TF_ROUND(29) TF_ROUND(16) TF_ROUND(24)
    x0 += k1; x1 += k2 + 4u;
    TF_ROUND(13) TF_ROUND(15) TF_ROUND(26) TF_ROUND(6)
    x0 += k2; x1 += k0 + 5u;
#undef TF_ROUND
    r0 = x0; r1 = x1;
}

// ---------------- Input spike generation (bitmask, ballot) ----------------
__global__ __launch_bounds__(256) void gen_spikes(const float* __restrict__ x,
                                                  uint64_t* __restrict__ Sin) {
    const int lane = threadIdx.x & 63;
    const int wid  = __builtin_amdgcn_readfirstlane(blockIdx.x * 4 + (threadIdx.x >> 6));
    if (wid >= T_STEPS * BATCH) return;
    const int b = wid % BATCH;

    for (int qw = 0; qw < 16; ++qw) {
        bool pred = false;
        const int f = qw * 64 + lane;
        if (f < IN_F) {
            const uint32_t i = (uint32_t)(wid * IN_F + f);
            uint32_t r0, r1;
            threefry2x32_42(0u, i, r0, r1);
            const uint32_t bits = r0 ^ r1;
            const uint32_t fbits = (bits >> 9) | 0x3f800000u;
            const float u = __uint_as_float(fbits) - 1.0f;
            float p = x[b * IN_F + f];
            p = fminf(fmaxf(p, 0.0f), 1.0f);
            pred = (u < p);
        }
        const uint64_t mask = __ballot((int)pred);
        if (lane == 0) Sin[(long long)wid * 16 + qw] = mask;
    }
}

// ------- Weight transpose+slab-pack: WTp[h/64][f][h%64] = W[h][f] ---------
// Each element written once; value for (k, col) bit-identical to verified
// layout — only the address changes (64-col contiguous slabs).
__global__ __launch_bounds__(256) void transpose_pack(const float* __restrict__ W,
                                                      float* __restrict__ WTp,
                                                      int H, int F) {
    const long long idx = (long long)blockIdx.x * blockDim.x + threadIdx.x;
    const long long tot = (long long)H * F;
    if (idx >= tot) return;
    const long long f = idx / H;
    const long long h = idx % H;
    WTp[((h >> 6) * (long long)F + f) * 64 + (h & 63)] = W[h * (long long)F + f];
}

// ------- Fused layer: lane=(t,b), SGPR weights, per-lane spike reads ------
// Bit-exact to Eigen gebp (verified R11-R20): per (b,t,col) element
// S += spike*w with k flat ascending (fma with 0/1 spike == exact cond-add;
// mul commutes, rounding identical), folds at global k % KCB == 0 via scalar
// countdown, tail fold, strict-f32 LIF.
// Mapping: lane = t + 25*b (50/64 lanes active), wave wv = col-chunk of 16
// (cols wv*16..+15 of the block's 64-col slab). Per k per wave:
//   1 x ds_read_b32 (per-lane spike float, conflict-free, const addr+imm)
//   8 x uniform v2f weight loads -> s_load (scalar pipe)
//   8 x v_pk_fma_f32 (SGPR-pair weight x splatted spike)
// LIF: A-dump to LDS (stride 51), remap thread=(b,col), strict recursion,
// per-wave ballot = output word.
template<int KCB, int KTOT, int IN_STRIDE, int HTOT>
__global__ __launch_bounds__(256, 4) void layer_fmac(
    const uint64_t* __restrict__ Bin,   // [T][B][IN_STRIDE] u64, bit index = k
    const float*    __restrict__ WTp,   // [H/64][KTOT][64] packed slabs
    uint64_t*       __restrict__ Bout)  // [T][B][HTOT/64]
{
    __shared__ alignas(16) float tile[KCHUNK * 64];   // 32 KB; reused as Abuf
    const int tid  = threadIdx.x;
    const int lane = tid & 63;
    const int wvu  = __builtin_amdgcn_readfirstlane(tid >> 6);
    const int NBP  = BATCH / 2;
    const int bp   = blockIdx.x % NBP;               // colslab-major grid
    const int cs   = blockIdx.x / NBP;
    const int b0   = bp * 2;
    const float* __restrict__ Wslab =
        WTp + (long long)cs * KTOT * 64 + wvu * 16;

    v2f S2[8], A2[8];
#pragma unroll
    for (int j = 0; j < 8; ++j) { S2[j] = (v2f)0.0f; A2[j] = (v2f)0.0f; }

    int nf = KCB;                       // next fold boundary (k+1 == nf)
    const int NCH = (KTOT + KCHUNK - 1) / KCHUNK;
    for (int c = 0; c < NCH; ++c) {
        const int k0 = c * KCHUNK;
        const int kv = (KTOT - k0 < KCHUNK) ? (KTOT - k0) : KCHUNK;
        __syncthreads();                // previous tile fully consumed
        const int NV = kv * 50;         // kv * (25 t x 2 b)
        for (int r = 0; r < (NV + 255) / 256; ++r) {
            const int idx = r * 256 + tid;
            if (idx < NV) {
                const int kk = (idx * 5243) >> 18;   // idx/50, exact < 43690
                const int tb = idx - kk * 50;
                const int bbf = (tb >= 25) ? 1 : 0;
                const int tf  = tb - 25 * bbf;
                const int k   = k0 + kk;
                const uint64_t word =
                    Bin[((long long)tf * BATCH + (b0 + bbf)) * IN_STRIDE + (k >> 6)];
                tile[kk * 64 + tb] = ((word >> (k & 63)) & 1ull) ? 1.0f : 0.0f;
            }
        }
        __syncthreads();

        for (int kk = 0; kk < kv; ++kk) {
            const float* wrow = Wslab + (long long)(k0 + kk) * 64;
            const v2f w0 = *(const v2f*)(wrow);
            const v2f w1 = *(const v2f*)(wrow + 2);
            const v2f w2 = *(const v2f*)(wrow + 4);
            const v2f w3 = *(const v2f*)(wrow + 6);
            const v2f w4 = *(const v2f*)(wrow + 8);
            const v2f w5 = *(const v2f*)(wrow + 10);
            const v2f w6 = *(const v2f*)(wrow + 12);
            const v2f w7 = *(const v2f*)(wrow + 14);
            const float sp = tile[kk * 64 + lane];   // per-lane spike float
            v2f sp2; sp2.x = sp; sp2.y = sp;
            S2[0] = __builtin_elementwise_fma(w0, sp2, S2[0]);
            S2[1] = __builtin_elementwise_fma(w1, sp2, S2[1]);
            S2[2] = __builtin_elementwise_fma(w2, sp2, S2[2]);
            S2[3] = __builtin_elementwise_fma(w3, sp2, S2[3]);
            S2[4] = __builtin_elementwise_fma(w4, sp2, S2[4]);
            S2[5] = __builtin_elementwise_fma(w5, sp2, S2[5]);
            S2[6] = __builtin_elementwise_fma(w6, sp2, S2[6]);
            S2[7] = __builtin_elementwise_fma(w7, sp2, S2[7]);
            if (k0 + kk + 1 == nf) {                // exact KC fold boundary
#pragma unroll
                for (int j = 0; j < 8; ++j) { A2[j] = A2[j] + S2[j]; S2[j] = (v2f)0.0f; }
                nf += KCB;
            }
        }
    }
    if (KTOT % KCB != 0) {
#pragma unroll
        for (int j = 0; j < 8; ++j) A2[j] = A2[j] + S2[j];
    }

    // ---- A-dump to LDS (stride 51: conflict-free both phases) ----
    __syncthreads();                    // tile fully consumed; reuse as Abuf
    float* Abuf = tile;                 // [col][51] : col*51 + (t + 25*b)
    if (lane < 50) {
#pragma unroll
        for (int j = 0; j < 8; ++j) {
            Abuf[(wvu * 16 + 2 * j) * 51 + lane]     = A2[j].x;
            Abuf[(wvu * 16 + 2 * j + 1) * 51 + lane] = A2[j].y;
        }
    }
    __syncthreads();

    // ---- LIF: thread = (b = tid>>6, col = lane), strict f32 (verified) ----
    if (tid < 128) {
        const int bb  = tid >> 6;
        const int col = lane;
        float m = 0.0f;
        for (int t = 0; t < T_STEPS; ++t) {
            const float ca = Abuf[col * 51 + t + 25 * bb];
            const float reset = (m > 1.0f) ? 1.0f : 0.0f;
            m = __fsub_rn(__fadd_rn(__fmul_rn(0.9f, m), ca), reset);
            const uint64_t mask = __ballot((int)(m > 1.0f));
            if (lane == 0)
                Bout[((long long)t * BATCH + (b0 + bb)) * (HTOT / 64) + cs] = mask;
        }
    }
}

// ---------------- Output layer (H=10): counts, blocked f32 (kc=280) -------
__global__ __launch_bounds__(256) void layer_out(const uint64_t* __restrict__ S1,
                                                 const float* __restrict__ W2,
                                                 float* __restrict__ out) {
    const int idx = blockIdx.x * blockDim.x + threadIdx.x;
    const int b = idx >> 4;   // 16 threads per batch row (10 used)
    const int o = idx & 15;
    if (b >= BATCH) return;

    float m = 0.0f;
    float cnt = 0.0f;
    for (int t = 0; t < T_STEPS; ++t) {
        float acc = 0.0f;
        float S = 0.0f;
        if (o < OUTF) {
            for (int qw = 0; qw < 64; ++qw) {
                const uint64_t sw = S1[((long long)t * BATCH + b) * 64 + qw];
                const float* wrow = W2 + (long long)o * HID + qw * 64;
#pragma unroll
                for (int fb = 0; fb < 64; ++fb) {
                    S = __fadd_rn(S, ((sw >> fb) & 1ull) ? wrow[fb] : 0.0f);
                    if (((qw * 64 + fb + 1) % KC_L1) == 0) {
                        acc = __fadd_rn(acc, S);
                        S = 0.0f;
                    }
                }
            }
            if (HID % KC_L1 != 0) acc = __fadd_rn(acc, S);
        }
        const float reset = (m > 1.0f) ? 1.0f : 0.0f;
        m = __fsub_rn(__fadd_rn(__fmul_rn(0.9f, m), acc), reset);
        if (m > 1.0f) cnt += 1.0f;
    }
    if (o < OUTF) out[b * OUTF + o] = cnt;
}

// ---------------- Launch ----------------
extern "C" void kernel_launch(void* const* d_in, const int* in_sizes, int n_in,
                              void* d_out, int out_size, void* d_ws, size_t ws_size,
                              hipStream_t stream) {
    const float* x  = (const float*)d_in[0];
    const float* W0 = (const float*)d_in[1];
    const float* W1 = (const float*)d_in[2];
    const float* W2 = (const float*)d_in[3];
    float* out = (float*)d_out;

    char* ws = (char*)d_ws;
    size_t off = 0;
    float* WT0 = (float*)(ws + off); off += (size_t)IN_F * HID * sizeof(float);   // 12.8 MB
    float* WT1 = (float*)(ws + off); off += (size_t)HID * HID * sizeof(float);    // 64 MB
    uint64_t* Sin = (uint64_t*)(ws + off); off += (size_t)T_STEPS * BATCH * 16 * 8; // 3.3 MB
    uint64_t* S0  = (uint64_t*)(ws + off); off += (size_t)T_STEPS * BATCH * 64 * 8; // 13.1 MB
    uint64_t* S1  = (uint64_t*)(ws + off); off += (size_t)T_STEPS * BATCH * 64 * 8; // 13.1 MB
    (void)off; (void)ws_size; (void)in_sizes; (void)n_in; (void)out_size;

    // 1) transpose + slab-pack weights (64-col contiguous slabs)
    {
        long long tot0 = (long long)HID * IN_F;
        transpose_pack<<<(int)((tot0 + 255) / 256), 256, 0, stream>>>(W0, WT0, HID, IN_F);
        long long tot1 = (long long)HID * HID;
        transpose_pack<<<(int)((tot1 + 255) / 256), 256, 0, stream>>>(W1, WT1, HID, HID);
    }
    // 2) Poisson spike raster via threefry (partitionable, XOR readout)
    gen_spikes<<<(T_STEPS * BATCH) / 4, 256, 0, stream>>>(x, Sin);
    // 3) layer 0: 784 -> 4096, kc=264
    layer_fmac<KC_L0, IN_F, 16, HID>
        <<<(HID / 64) * (BATCH / 2), 256, 0, stream>>>(Sin, WT0, S0);
    // 4) layer 1: 4096 -> 4096, kc=280
    layer_fmac<KC_L1, HID, 64, HID>
        <<<(HID / 64) * (BATCH / 2), 256, 0, stream>>>(S0, WT1, S1);
    // 5) layer 2: 4096 -> 10, kc=280, spike counts
    layer_out<<<BATCH * 16 / 256, 256, 0, stream>>>(S1, W2, out);
}

// Round 22
// 20285.402 us; speedup vs baseline: 2.7603x; 2.7603x over previous
//
#include <hip/hip_runtime.h>
#include <stdint.h>

#define T_STEPS 25
#define BATCH   1024
#define IN_F    784
#define HID     4096
#define OUTF    10
// Eigen SINGLE-THREADED gebp blocking (verified bit-exact R11-R21):
// max_kc=288 evened -> kc(784)=264 (264+264+256), kc(4096)=280 (14x280+176).
#define KC_L0   264
#define KC_L1   280
#define KCHUNK  128
#define SLABC   512     // columns per slab (per block); thread owns tid, tid+256

typedef float v2f __attribute__((ext_vector_type(2)));

// ---------------- Threefry-2x32, key = (0, 42), 20 rounds ----------------
__device__ __forceinline__ uint32_t rotl32(uint32_t x, int d) {
    return (x << d) | (x >> (32 - d));
}

__device__ __forceinline__ void threefry2x32_42(uint32_t x0, uint32_t x1,
                                                uint32_t& r0, uint32_t& r1) {
    const uint32_t k0 = 0u, k1 = 42u;
    const uint32_t k2 = k0 ^ k1 ^ 0x1BD11BDAu;
    x0 += k0; x1 += k1;
#define TF_ROUND(r) { x0 += x1; x1 = rotl32(x1, r); x1 ^= x0; }
    TF_ROUND(13) TF_ROUND(15) TF_ROUND(26) TF_ROUND(6)
    x0 += k1; x1 += k2 + 1u;
    TF_ROUND(17) TF_ROUND(29) TF_ROUND(16) TF_ROUND(24)
    x0 += k2; x1 += k0 + 2u;
    TF_ROUND(13) TF_ROUND(15) TF_ROUND(26) TF_ROUND(6)
    x0 += k0; x1 += k1 + 3u;
    TF_ROUND(17) TF_ROUND(29) TF_ROUND(16) TF_ROUND(24)
    x0 += k1; x1 += k2 + 4u;
    TF_ROUND(13) TF_ROUND(15) TF_ROUND(26) TF_ROUND(6)
    x0 += k2; x1 += k0 + 5u;
#undef TF_ROUND
    r0 = x0; r1 = x1;
}

// ---------------- Input spike generation (bitmask, ballot) ----------------
__global__ __launch_bounds__(256) void gen_spikes(const float* __restrict__ x,
                                                  uint64_t* __restrict__ Sin) {
    const int lane = threadIdx.x & 63;
    const int wid  = __builtin_amdgcn_readfirstlane(blockIdx.x * 4 + (threadIdx.x >> 6));
    if (wid >= T_STEPS * BATCH) return;
    const int b = wid % BATCH;

    for (int qw = 0; qw < 16; ++qw) {
        bool pred = false;
        const int f = qw * 64 + lane;
        if (f < IN_F) {
            const uint32_t i = (uint32_t)(wid * IN_F + f);
            uint32_t r0, r1;
            threefry2x32_42(0u, i, r0, r1);
            const uint32_t bits = r0 ^ r1;
            const uint32_t fbits = (bits >> 9) | 0x3f800000u;
            const float u = __uint_as_float(fbits) - 1.0f;
            float p = x[b * IN_F + f];
            p = fminf(fmaxf(p, 0.0f), 1.0f);
            pred = (u < p);
        }
        const uint64_t mask = __ballot((int)pred);
        if (lane == 0) Sin[(long long)wid * 16 + qw] = mask;
    }
}

// ------- Weight transpose+slab-pack: WTp[h/512][f][h%512] = W[h][f] -------
// Each element written once; value for (k, col) bit-identical to verified
// layout — only the address changes (512-col contiguous slabs, as R19).
__global__ __launch_bounds__(256) void transpose_pack(const float* __restrict__ W,
                                                      float* __restrict__ WTp,
                                                      int H, int F) {
    const long long idx = (long long)blockIdx.x * blockDim.x + threadIdx.x;
    const long long tot = (long long)H * F;
    if (idx >= tot) return;
    const long long f = idx / H;
    const long long h = idx % H;
    const long long hb = h >> 9;          // h / 512
    const long long c  = h & 511;         // h % 512
    WTp[(hb * F + f) * SLABC + c] = W[h * (long long)F + f];
}

// -------- Fused layer: 2 cols x 2 batch rows per thread (C=2, NB=2) -------
// Bit-exact to Eigen gebp (verified R11-R21): per (b,col) element,
// S[t] += fbit*w with k flat ascending, folds at global k % KCB == 0 via
// scalar countdown, tail fold, strict-f32 LIF.
// Tile [k][t][2b] floats (stride 52): one uniform ds_read_b128 = (t,t+1)x
// (b0,b1) -> feeds 4 pk-FMA (2 cols). Per wave-k: 13 DS + 2 coalesced
// weight dwords + 50 pk-FMA. v2f ops are per-component IEEE.
template<int KCB, int KTOT, int IN_STRIDE, int HTOT>
__global__ __launch_bounds__(256, 2) void layer_fmac(
    const uint64_t* __restrict__ Bin,   // [T][B][IN_STRIDE] u64, bit index = k
    const float*    __restrict__ WTp,   // [H/512][KTOT][512] packed slabs
    uint64_t*       __restrict__ Bout)  // [T][B][HTOT/64]
{
    __shared__ alignas(16) float tile[KCHUNK * 52];   // 26.6 KB
    const int tid  = threadIdx.x;
    const int lane = tid & 63;
    const int wv   = tid >> 6;
    const int NBP  = BATCH / 2;
    const int bp   = blockIdx.x % NBP;               // slab-major grid
    const int cs   = blockIdx.x / NBP;
    const int b0   = bp * 2;
    const float* __restrict__ Wslab = WTp + (long long)cs * KTOT * SLABC;

    v2f S[50], A[50];                   // [c*25 + t], components = (b0,b1)
#pragma unroll
    for (int j = 0; j < 50; ++j) { S[j] = (v2f)0.0f; A[j] = (v2f)0.0f; }

    int nf = KCB;                       // next fold boundary (k+1 == nf)
    const int NCH = (KTOT + KCHUNK - 1) / KCHUNK;
    for (int c = 0; c < NCH; ++c) {
        const int k0 = c * KCHUNK;
        const int kv = (KTOT - k0 < KCHUNK) ? (KTOT - k0) : KCHUNK;
        __syncthreads();                // previous tile fully consumed
        const int NV = kv * 50;         // kv * 25 t * 2 b
        for (int r = 0; r < (NV + 255) / 256; ++r) {
            const int idx = r * 256 + tid;
            if (idx < NV) {
                const int kk  = (idx * 5243) >> 18;  // idx/50, exact < 43690
                const int rem = idx - kk * 50;
                const int t   = rem >> 1;
                const int bb  = rem & 1;
                const int k   = k0 + kk;
                const uint64_t word =
                    Bin[((long long)t * BATCH + (b0 + bb)) * IN_STRIDE + (k >> 6)];
                tile[kk * 52 + rem] = ((word >> (k & 63)) & 1ull) ? 1.0f : 0.0f;
            }
        }
        __syncthreads();

        float wa = Wslab[(long long)k0 * SLABC + tid];
        float wb = Wslab[(long long)k0 * SLABC + 256 + tid];
        for (int kk = 0; kk < kv; ++kk) {
            const int kn = (kk + 1 < kv) ? kk + 1 : kv - 1;   // clamped prefetch
            const float wan = Wslab[(long long)(k0 + kn) * SLABC + tid];
            const float wbn = Wslab[(long long)(k0 + kn) * SLABC + 256 + tid];
            const float* fb = &tile[kk * 52];
            v2f wa2; wa2.x = wa; wa2.y = wa;
            v2f wb2; wb2.x = wb; wb2.y = wb;
#pragma unroll
            for (int j = 0; j < 12; ++j) {          // 12 x uniform ds_read_b128
                const float4 f = *(const float4*)(fb + 4 * j);
                v2f lo; lo.x = f.x; lo.y = f.y;     // t=2j   (b0,b1)
                v2f hi; hi.x = f.z; hi.y = f.w;     // t=2j+1 (b0,b1)
                S[2 * j]          = __builtin_elementwise_fma(lo, wa2, S[2 * j]);
                S[2 * j + 1]      = __builtin_elementwise_fma(hi, wa2, S[2 * j + 1]);
                S[25 + 2 * j]     = __builtin_elementwise_fma(lo, wb2, S[25 + 2 * j]);
                S[25 + 2 * j + 1] = __builtin_elementwise_fma(hi, wb2, S[25 + 2 * j + 1]);
            }
            {   const v2f f24 = *(const v2f*)(fb + 48);       // t=24 (b64)
                S[24] = __builtin_elementwise_fma(f24, wa2, S[24]);
                S[49] = __builtin_elementwise_fma(f24, wb2, S[49]); }
            if (k0 + kk + 1 == nf) {                // exact KC fold boundary
#pragma unroll
                for (int j = 0; j < 50; ++j) { A[j] = A[j] + S[j]; S[j] = (v2f)0.0f; }
                nf += KCB;
            }
            wa = wan; wb = wbn;
        }
    }
    if (KTOT % KCB != 0) {
#pragma unroll
        for (int j = 0; j < 50; ++j) A[j] = A[j] + S[j];
    }

    // LIF recursion: 2 cols x 2 b per thread, strict f32 (verified R11)
#pragma unroll
    for (int cc = 0; cc < 2; ++cc) {
#pragma unroll
        for (int bb = 0; bb < 2; ++bb) {
            float m = 0.0f;
#pragma unroll
            for (int t = 0; t < T_STEPS; ++t) {
                const v2f a = A[cc * 25 + t];
                const float ca = bb ? a.y : a.x;
                const float reset = (m > 1.0f) ? 1.0f : 0.0f;
                m = __fsub_rn(__fadd_rn(__fmul_rn(0.9f, m), ca), reset);
                const uint64_t mask = __ballot((int)(m > 1.0f));
                if (lane == 0)
                    Bout[((long long)t * BATCH + (b0 + bb)) * (HTOT / 64)
                         + cs * 8 + cc * 4 + wv] = mask;
            }
        }
    }
}

// ---------------- Output layer (H=10): counts, blocked f32 (kc=280) -------
__global__ __launch_bounds__(256) void layer_out(const uint64_t* __restrict__ S1,
                                                 const float* __restrict__ W2,
                                                 float* __restrict__ out) {
    const int idx = blockIdx.x * blockDim.x + threadIdx.x;
    const int b = idx >> 4;   // 16 threads per batch row (10 used)
    const int o = idx & 15;
    if (b >= BATCH) return;

    float m = 0.0f;
    float cnt = 0.0f;
    for (int t = 0; t < T_STEPS; ++t) {
        float acc = 0.0f;
        float S = 0.0f;
        if (o < OUTF) {
            for (int qw = 0; qw < 64; ++qw) {
                const uint64_t sw = S1[((long long)t * BATCH + b) * 64 + qw];
                const float* wrow = W2 + (long long)o * HID + qw * 64;
#pragma unroll
                for (int fb = 0; fb < 64; ++fb) {
                    S = __fadd_rn(S, ((sw >> fb) & 1ull) ? wrow[fb] : 0.0f);
                    if (((qw * 64 + fb + 1) % KC_L1) == 0) {
                        acc = __fadd_rn(acc, S);
                        S = 0.0f;
                    }
                }
            }
            if (HID % KC_L1 != 0) acc = __fadd_rn(acc, S);
        }
        const float reset = (m > 1.0f) ? 1.0f : 0.0f;
        m = __fsub_rn(__fadd_rn(__fmul_rn(0.9f, m), acc), reset);
        if (m > 1.0f) cnt += 1.0f;
    }
    if (o < OUTF) out[b * OUTF + o] = cnt;
}

// ---------------- Launch ----------------
extern "C" void kernel_launch(void* const* d_in, const int* in_sizes, int n_in,
                              void* d_out, int out_size, void* d_ws, size_t ws_size,
                              hipStream_t stream) {
    const float* x  = (const float*)d_in[0];
    const float* W0 = (const float*)d_in[1];
    const float* W1 = (const float*)d_in[2];
    const float* W2 = (const float*)d_in[3];
    float* out = (float*)d_out;

    char* ws = (char*)d_ws;
    size_t off = 0;
    float* WT0 = (float*)(ws + off); off += (size_t)IN_F * HID * sizeof(float);   // 12.8 MB
    float* WT1 = (float*)(ws + off); off += (size_t)HID * HID * sizeof(float);    // 64 MB
    uint64_t* Sin = (uint64_t*)(ws + off); off += (size_t)T_STEPS * BATCH * 16 * 8; // 3.3 MB
    uint64_t* S0  = (uint64_t*)(ws + off); off += (size_t)T_STEPS * BATCH * 64 * 8; // 13.1 MB
    uint64_t* S1  = (uint64_t*)(ws + off); off += (size_t)T_STEPS * BATCH * 64 * 8; // 13.1 MB
    (void)off; (void)ws_size; (void)in_sizes; (void)n_in; (void)out_size;

    // 1) transpose + slab-pack weights (512-col contiguous slabs)
    {
        long long tot0 = (long long)HID * IN_F;
        transpose_pack<<<(int)((tot0 + 255) / 256), 256, 0, stream>>>(W0, WT0, HID, IN_F);
        long long tot1 = (long long)HID * HID;
        transpose_pack<<<(int)((tot1 + 255) / 256), 256, 0, stream>>>(W1, WT1, HID, HID);
    }
    // 2) Poisson spike raster via threefry (partitionable, XOR readout)
    gen_spikes<<<(T_STEPS * BATCH) / 4, 256, 0, stream>>>(x, Sin);
    // 3) layer 0: 784 -> 4096, kc=264
    layer_fmac<KC_L0, IN_F, 16, HID>
        <<<(HID / SLABC) * (BATCH / 2), 256, 0, stream>>>(Sin, WT0, S0);
    // 4) layer 1: 4096 -> 4096, kc=280
    layer_fmac<KC_L1, HID, 64, HID>
        <<<(HID / SLABC) * (BATCH / 2), 256, 0, stream>>>(S0, WT1, S1);
    // 5) layer 2: 4096 -> 10, kc=280, spike counts
    layer_out<<<BATCH * 16 / 256, 256, 0, stream>>>(S1, W2, out);
}